// Round 1
// 259.256 us; speedup vs baseline: 1.1441x; 1.1441x over previous
//
#include <hip/hip_runtime.h>
#include <math.h>

#define BB 32
#define CC 256
#define HH 64
#define WW 64
#define HWSZ (HH * WW)   // 4096
#define NCHUNK 16        // hw chunks per image
// chunk = 256 positions = 64 lanes x float4

// ---------------------------------------------------------------------------
// Kernel 1: one pass over x. Grid: 32 b x 16 hw-chunks = 512 blocks, 256 thr.
// Block owns (b, 256 hw positions) for ALL 256 channels:
//   wave w handles channels [64w, 64w+64); lane l owns float4 at hw0+4l.
// Pool max/sum partials stay in registers per wave, merged via LDS, written
// once with plain float4 stores -> ZERO pool atomics (was 4.2M atomics,
// ~68 MB of TCC write-through + serialization).
// Per-channel sums: groups of 16 channels, butterfly once per channel,
// lane0 stores 16 contiguous partials -> no atomics anywhere.
// ---------------------------------------------------------------------------
__global__ __launch_bounds__(256, 2) void stats_kernel(
    const float* __restrict__ x, float* __restrict__ chan_part,
    float* __restrict__ pool_max, float* __restrict__ pool_sum) {
  const int b = blockIdx.x >> 4;
  const int chunk = blockIdx.x & 15;
  const int hw0 = chunk << 8;           // 256 positions per chunk
  const int tid = threadIdx.x;
  const int wave = tid >> 6;
  const int lane = tid & 63;
  const int c_base = wave << 6;         // 64 channels per wave

  const float4* xp =
      (const float4*)(x + ((size_t)b << 20) + ((size_t)c_base << 12) + hw0) + lane;

  float4 mx = make_float4(-3.4e38f, -3.4e38f, -3.4e38f, -3.4e38f);
  float4 sm = make_float4(0.f, 0.f, 0.f, 0.f);

  for (int g = 0; g < 4; ++g) {
    float s[16];
    // 16 independent loads pipeline freely (no cross-lane ops in this loop).
#pragma unroll
    for (int ci = 0; ci < 16; ++ci) {
      const float4 v = xp[(g * 16 + ci) * (HWSZ / 4)];
      mx.x = fmaxf(mx.x, v.x); mx.y = fmaxf(mx.y, v.y);
      mx.z = fmaxf(mx.z, v.z); mx.w = fmaxf(mx.w, v.w);
      sm.x += v.x; sm.y += v.y; sm.z += v.z; sm.w += v.w;
      s[ci] = (v.x + v.y) + (v.z + v.w);
    }
    // 16 independent 6-deep butterfly chains.
#pragma unroll
    for (int ci = 0; ci < 16; ++ci) {
      float v = s[ci];
#pragma unroll
      for (int off = 32; off > 0; off >>= 1) v += __shfl_xor(v, off, 64);
      s[ci] = v;
    }
    if (lane == 0) {
      float4* cp = (float4*)(chan_part +
                             ((size_t)(b * NCHUNK + chunk)) * CC + c_base + g * 16);
      cp[0] = make_float4(s[0],  s[1],  s[2],  s[3]);
      cp[1] = make_float4(s[4],  s[5],  s[6],  s[7]);
      cp[2] = make_float4(s[8],  s[9],  s[10], s[11]);
      cp[3] = make_float4(s[12], s[13], s[14], s[15]);
    }
  }

  // Merge the 4 waves' pool partials (covering disjoint channel quarters)
  // through LDS; wave 0 writes the final per-position max/sum directly.
  __shared__ float4 lmax[4][64];
  __shared__ float4 lsum[4][64];
  lmax[wave][lane] = mx;
  lsum[wave][lane] = sm;
  __syncthreads();
  if (tid < 64) {
    const float4 a = lmax[0][tid], b4 = lmax[1][tid];
    const float4 c4 = lmax[2][tid], d4 = lmax[3][tid];
    float4 M;
    M.x = fmaxf(fmaxf(a.x, b4.x), fmaxf(c4.x, d4.x));
    M.y = fmaxf(fmaxf(a.y, b4.y), fmaxf(c4.y, d4.y));
    M.z = fmaxf(fmaxf(a.z, b4.z), fmaxf(c4.z, d4.z));
    M.w = fmaxf(fmaxf(a.w, b4.w), fmaxf(c4.w, d4.w));
    const float4 sa = lsum[0][tid], sb = lsum[1][tid];
    const float4 sc = lsum[2][tid], sd = lsum[3][tid];
    float4 S;
    S.x = (sa.x + sb.x) + (sc.x + sd.x);
    S.y = (sa.y + sb.y) + (sc.y + sd.y);
    S.z = (sa.z + sb.z) + (sc.z + sd.z);
    S.w = (sa.w + sb.w) + (sc.w + sd.w);
    ((float4*)(pool_max + ((size_t)b << 12) + hw0))[tid] = M;
    ((float4*)(pool_sum + ((size_t)b << 12) + hw0))[tid] = S;
  }
}

// ---------------------------------------------------------------------------
// Kernel 2: ECA — fold 16 chunk-partials, conv1d(k=5, pad=2), sigmoid.
// ---------------------------------------------------------------------------
__global__ __launch_bounds__(256) void eca_kernel(
    const float* __restrict__ chan_part, const float* __restrict__ w5,
    float* __restrict__ ch_w) {
  __shared__ float m[CC];
  const int b = blockIdx.x;
  const int c = threadIdx.x;
  float s = 0.0f;
#pragma unroll
  for (int k = 0; k < NCHUNK; ++k) s += chan_part[(size_t)(b * NCHUNK + k) * CC + c];
  m[c] = s * (1.0f / HWSZ);
  __syncthreads();

  float acc = 0.0f;
#pragma unroll
  for (int k = 0; k < 5; ++k) {
    int cc = c + k - 2;
    float v = (cc >= 0 && cc < CC) ? m[cc] : 0.0f;
    acc = fmaf(v, w5[k], acc);
  }
  ch_w[b * CC + c] = 1.0f / (1.0f + __expf(-acc));
}

// ---------------------------------------------------------------------------
// Kernel 3: spatial attention — 7x7 conv (max, sum/256), pad 3, +bias, sigmoid.
// ---------------------------------------------------------------------------
__global__ __launch_bounds__(256) void spatial_kernel(
    const float* __restrict__ pool_max, const float* __restrict__ pool_sum,
    const float* __restrict__ w2, const float* __restrict__ bias,
    float* __restrict__ sp) {
  const int idx = blockIdx.x * 256 + threadIdx.x;  // over B*HW
  const int b = idx >> 12;
  const int hw = idx & (HWSZ - 1);
  const int h = hw >> 6;
  const int w = hw & 63;

  float acc = bias[0];
#pragma unroll
  for (int kh = 0; kh < 7; ++kh) {
    const int hh = h + kh - 3;
    if (hh < 0 || hh >= HH) continue;
#pragma unroll
    for (int kw = 0; kw < 7; ++kw) {
      const int ww = w + kw - 3;
      if (ww < 0 || ww >= WW) continue;
      const int off = b * HWSZ + hh * WW + ww;
      acc = fmaf(pool_max[off], w2[kh * 7 + kw], acc);
      acc = fmaf(pool_sum[off], w2[49 + kh * 7 + kw] * (1.0f / CC), acc);
    }
  }
  sp[idx] = 1.0f / (1.0f + __expf(-acc));
}

// ---------------------------------------------------------------------------
// Kernel 4: out = x * (ch_w[b,c] + sp[b,hw] + 1).  float4 streaming.
// ---------------------------------------------------------------------------
__global__ __launch_bounds__(256) void combine_kernel(
    const float* __restrict__ x, const float* __restrict__ ch_w,
    const float* __restrict__ sp, float* __restrict__ out) {
  const size_t f = (size_t)blockIdx.x * 256 + threadIdx.x;  // float4 index
  const size_t e = f * 4;                                   // element index
  const int b = (int)(e >> 20);          // C*HW = 2^20
  const int c = (int)(e >> 12) & 255;    // HW = 2^12
  const int hw = (int)e & (HWSZ - 1);

  const float4 x4 = ((const float4*)x)[f];
  const float4 s4 = ((const float4*)(sp + ((size_t)b << 12)))[hw >> 2];
  const float cw = ch_w[b * CC + c] + 1.0f;

  float4 o;
  o.x = x4.x * (cw + s4.x);
  o.y = x4.y * (cw + s4.y);
  o.z = x4.z * (cw + s4.z);
  o.w = x4.w * (cw + s4.w);
  ((float4*)out)[f] = o;
}

extern "C" void kernel_launch(void* const* d_in, const int* in_sizes, int n_in,
                              void* d_out, int out_size, void* d_ws, size_t ws_size,
                              hipStream_t stream) {
  const float* x    = (const float*)d_in[0];  // (32,256,64,64)
  const float* w1   = (const float*)d_in[1];  // (1,1,5)
  const float* w2   = (const float*)d_in[2];  // (1,2,7,7)
  const float* bias = (const float*)d_in[3];  // (1,)
  float* out = (float*)d_out;

  float* ws = (float*)d_ws;
  float* chan_part = ws;                       // 32*16*256 = 131072 floats
  float* ch_w      = ws + 131072;              // 8192
  float* pool_max  = ws + 139264;              // 131072
  float* pool_sum  = ws + 270336;              // 131072
  float* sp        = ws + 401408;              // 131072
  // Every workspace word is fully written before it is read -> no memsets,
  // no atomics, no init-pattern dependence.

  stats_kernel<<<BB * NCHUNK, 256, 0, stream>>>(x, chan_part, pool_max, pool_sum);
  eca_kernel<<<BB, 256, 0, stream>>>(chan_part, w1, ch_w);
  spatial_kernel<<<(BB * HWSZ) / 256, 256, 0, stream>>>(pool_max, pool_sum, w2, bias, sp);
  combine_kernel<<<(BB * CC * HWSZ) / (4 * 256), 256, 0, stream>>>(x, ch_w, sp, out);
}